// Round 6
// baseline (434.605 us; speedup 1.0000x reference)
//
#include <hip/hip_runtime.h>
#include <hip/hip_cooperative_groups.h>
#include <stdint.h>

#pragma clang fp contract(off)

namespace cg = cooperative_groups;

namespace {
constexpr int B_ = 2, V_ = 2, HC = 512, WC = 512, HF = 256, WF = 256, CF = 64;
constexpr int NPIX = HF * WF;                 // 65536
constexpr float EPSF = 1e-4f;
constexpr float BIGF = 1e10f;                 // exactly representable in f32
constexpr int NPT = B_ * V_ * NPIX;           // 262144
constexpr int NBLK = 1024;                    // cooperative grid; NPT/256 exactly
constexpr int RESIZE_BLKS = (B_ * V_ * 3 * NPIX) / 256;   // 3072
constexpr int TP_BLKS = B_ * V_ * (NPIX / 64);            // 4096 (64px x 64ch tiles)
// workspace layout: zwin (2 MiB) | colr (3 MiB) | mats (256 B) | tf (64 MiB, optional)
constexpr size_t WS_BASE = (size_t)NPT * 8 + (size_t)B_ * V_ * 3 * NPIX * 4 + 256;
constexpr size_t TF_BYTES = (size_t)NPT * CF * 4;
}

// NON-FMA ascending f32 dot4 (fp contract off TU-wide keeps mul/add separate).
__device__ __forceinline__ float dot4f(const float* __restrict__ r,
                                       float v0, float v1, float v2, float v3) {
  float t = r[0] * v0;
  t = t + r[1] * v1;
  t = t + r[2] * v2;
  t = t + r[3] * v3;
  return t;
}

// per-batch sK / sKinv (f64 adjugate -> f32). Executed by thread b (b < B_).
__device__ void mats_compute(const float* __restrict__ K, int b,
                             float* __restrict__ mats) {
  const float rowscale[4] = {0.5f, 0.5f, 1.0f, 1.0f};
  float sK[16];
  for (int i = 0; i < 4; ++i)
    for (int j = 0; j < 4; ++j)
      sK[i*4+j] = K[b*16 + i*4 + j] * rowscale[i];
  double m[16];
  for (int i = 0; i < 16; ++i) m[i] = (double)sK[i];
  double inv[16];
  inv[0]  =  m[5]*m[10]*m[15] - m[5]*m[11]*m[14] - m[9]*m[6]*m[15] + m[9]*m[7]*m[14] + m[13]*m[6]*m[11] - m[13]*m[7]*m[10];
  inv[4]  = -m[4]*m[10]*m[15] + m[4]*m[11]*m[14] + m[8]*m[6]*m[15] - m[8]*m[7]*m[14] - m[12]*m[6]*m[11] + m[12]*m[7]*m[10];
  inv[8]  =  m[4]*m[9]*m[15]  - m[4]*m[11]*m[13] - m[8]*m[5]*m[15] + m[8]*m[7]*m[13] + m[12]*m[5]*m[11] - m[12]*m[7]*m[9];
  inv[12] = -m[4]*m[9]*m[14]  + m[4]*m[10]*m[13] + m[8]*m[5]*m[14] - m[8]*m[6]*m[13] - m[12]*m[5]*m[10] + m[12]*m[6]*m[9];
  inv[1]  = -m[1]*m[10]*m[15] + m[1]*m[11]*m[14] + m[9]*m[2]*m[15] - m[9]*m[3]*m[14] - m[13]*m[2]*m[11] + m[13]*m[3]*m[10];
  inv[5]  =  m[0]*m[10]*m[15] - m[0]*m[11]*m[14] - m[8]*m[2]*m[15] + m[8]*m[3]*m[14] + m[12]*m[2]*m[11] - m[12]*m[3]*m[10];
  inv[9]  = -m[0]*m[9]*m[15]  + m[0]*m[11]*m[13] + m[8]*m[1]*m[15] - m[8]*m[3]*m[13] - m[12]*m[1]*m[11] + m[12]*m[3]*m[9];
  inv[13] =  m[0]*m[9]*m[14]  - m[0]*m[10]*m[13] - m[8]*m[1]*m[14] + m[8]*m[2]*m[13] + m[12]*m[1]*m[10] - m[12]*m[2]*m[9];
  inv[2]  =  m[1]*m[6]*m[15]  - m[1]*m[7]*m[14]  - m[5]*m[2]*m[15] + m[5]*m[3]*m[14] + m[13]*m[2]*m[7]  - m[13]*m[3]*m[6];
  inv[6]  = -m[0]*m[6]*m[15]  + m[0]*m[7]*m[14]  + m[4]*m[2]*m[15] - m[4]*m[3]*m[14] - m[12]*m[2]*m[7]  + m[12]*m[3]*m[6];
  inv[10] =  m[0]*m[5]*m[15]  - m[0]*m[7]*m[13]  - m[4]*m[1]*m[15] + m[4]*m[3]*m[13] + m[12]*m[1]*m[7]  - m[12]*m[3]*m[5];
  inv[14] = -m[0]*m[5]*m[14]  + m[0]*m[6]*m[13]  + m[4]*m[1]*m[14] - m[4]*m[2]*m[13] - m[12]*m[1]*m[6]  + m[12]*m[2]*m[5];
  inv[3]  = -m[1]*m[6]*m[11]  + m[1]*m[7]*m[10]  + m[5]*m[2]*m[11] - m[5]*m[3]*m[10] - m[9]*m[2]*m[7]   + m[9]*m[3]*m[6];
  inv[7]  =  m[0]*m[6]*m[11]  - m[0]*m[7]*m[10]  - m[4]*m[2]*m[11] + m[4]*m[3]*m[10] + m[8]*m[2]*m[7]   - m[8]*m[3]*m[6];
  inv[11] = -m[0]*m[5]*m[11]  + m[0]*m[7]*m[9]   + m[4]*m[1]*m[11] - m[4]*m[3]*m[9]  - m[8]*m[1]*m[7]   + m[8]*m[3]*m[5];
  inv[15] =  m[0]*m[5]*m[10]  - m[0]*m[6]*m[9]   - m[4]*m[1]*m[10] + m[4]*m[2]*m[9]  + m[8]*m[1]*m[6]   - m[8]*m[2]*m[5];
  double det = m[0]*inv[0] + m[1]*inv[4] + m[2]*inv[8] + m[3]*inv[12];
  double idet = 1.0 / det;
  for (int i = 0; i < 16; ++i) {
    mats[b*32 + i]      = sK[i];
    mats[b*32 + 16 + i] = (float)(inv[i] * idet);
  }
}

// feats transpose tile (bv,c,pix)->(bv,pix,c): 64px x 64ch, 4x4 register
// micro-tile per thread (r5-verified). tid in [0, TP_BLKS).
__device__ __forceinline__ void transp_tile(int tid, int t,
                                            const float* __restrict__ feats,
                                            float* __restrict__ tf) {
  int bv = tid >> 10;                  // 1024 tiles per bv (64 px each)
  int pix0 = (tid & 1023) << 6;
  int c4 = t >> 4;                     // 0..15 -> channels 4*c4..4*c4+3
  int p4 = t & 15;                     // 0..15 -> pixels 4*p4..4*p4+3
  const float* fb = feats + (size_t)bv * CF * NPIX + pix0 + 4 * p4;
  float4 v0 = *(const float4*)(fb + (size_t)(4 * c4 + 0) * NPIX);
  float4 v1 = *(const float4*)(fb + (size_t)(4 * c4 + 1) * NPIX);
  float4 v2 = *(const float4*)(fb + (size_t)(4 * c4 + 2) * NPIX);
  float4 v3 = *(const float4*)(fb + (size_t)(4 * c4 + 3) * NPIX);
  float* tb = tf + ((size_t)bv * NPIX + pix0 + 4 * p4) * CF + 4 * c4;
  *(float4*)(tb + 0 * CF) = make_float4(v0.x, v1.x, v2.x, v3.x);
  *(float4*)(tb + 1 * CF) = make_float4(v0.y, v1.y, v2.y, v3.y);
  *(float4*)(tb + 2 * CF) = make_float4(v0.z, v1.z, v2.z, v3.z);
  *(float4*)(tb + 3 * CF) = make_float4(v0.w, v1.w, v2.w, v3.w);
}

// antialiased linear 2x downsample of colors (r5 arithmetic). g < 3*NPT/... exact.
__device__ __forceinline__ void resize_body(int g,
                                            const float* __restrict__ colors,
                                            float* __restrict__ colr) {
  int pc  = g >> 16;            // bv*3 + ch
  int pix = g & (NPIX - 1);
  int y = pix >> 8, x = pix & (WF - 1);
  const float* src = colors + (size_t)pc * HC * WC;
  const float W37 = (float)(3.0 / 7.0), W17 = (float)(1.0 / 7.0);
  float wy[4] = {0.125f, 0.375f, 0.375f, 0.125f};
  float wx[4] = {0.125f, 0.375f, 0.375f, 0.125f};
  if (y == 0)      { wy[0] = 0.f; wy[1] = W37; wy[2] = W37; wy[3] = W17; }
  if (y == HF - 1) { wy[0] = W17; wy[1] = W37; wy[2] = W37; wy[3] = 0.f; }
  if (x == 0)      { wx[0] = 0.f; wx[1] = W37; wx[2] = W37; wx[3] = W17; }
  if (x == WF - 1) { wx[0] = W17; wx[1] = W37; wx[2] = W37; wx[3] = 0.f; }
  int jy0 = 2 * y - 1, jx0 = 2 * x - 1;
  float acc = 0.f;
  #pragma unroll
  for (int ty = 0; ty < 4; ++ty) {
    if (wy[ty] == 0.f) continue;       // also guards OOB rows
    int jy = jy0 + ty;
    float rs = 0.f;
    #pragma unroll
    for (int tx = 0; tx < 4; ++tx) {
      if (wx[tx] == 0.f) continue;     // also guards OOB cols
      rs = rs + wx[tx] * src[(size_t)jy * WC + (jx0 + tx)];
    }
    acc = acc + wy[ty] * rs;
  }
  colr[g] = acc;
}

// f32 projection + z-buffer atomicMin. Arithmetic byte-identical to the r5
// PASSING kernel; control flow restructured WITHOUT early returns so it is
// safe before grid.sync(). (!(c) return  <->  if (c) {}, NaN semantics kept.)
__device__ __forceinline__ void splat_body(int g,
                                           const float* __restrict__ depths,
                                           const float* __restrict__ mats,
                                           const float* __restrict__ srcRTinv,
                                           const float* __restrict__ dstRT,
                                           unsigned long long* __restrict__ zwin) {
  int bv = g >> 16;
  int n  = g & (NPIX - 1);
  int b  = bv / V_;
  int y = n >> 8, x = n & (WF - 1);
  // nearest resize 512->256 picks input index floor((i+0.5)*2) = 2i+1
  float d = depths[(size_t)bv * HC * WC + (size_t)(2 * y + 1) * WC + (2 * x + 1)];
  // jax-native f32 linspace(-1,1,256): step32 = fl32(2/255)
  const float step32 = 2.0f / 255.0f;
  float xf = (float)x * step32 - 1.0f;
  float yf = (float)y * step32 - 1.0f;
  float pr0 = xf * d, pr1 = yf * d, pr2 = d, pr3 = 1.0f;
  const float* sK  = mats + b * 32;
  const float* sKi = mats + b * 32 + 16;
  const float* Rs  = srcRTinv + (size_t)bv * 16;
  const float* Rd  = dstRT + (size_t)b * 16;     // dst_RTs[:,0]
  float a0 = dot4f(sKi + 0,  pr0, pr1, pr2, pr3);
  float a1 = dot4f(sKi + 4,  pr0, pr1, pr2, pr3);
  float a2 = dot4f(sKi + 8,  pr0, pr1, pr2, pr3);
  float a3 = dot4f(sKi + 12, pr0, pr1, pr2, pr3);
  float w0 = dot4f(Rs + 0,  a0, a1, a2, a3);
  float w1 = dot4f(Rs + 4,  a0, a1, a2, a3);
  float w2 = dot4f(Rs + 8,  a0, a1, a2, a3);
  float w3 = dot4f(Rs + 12, a0, a1, a2, a3);
  float c0 = dot4f(Rd + 0,  w0, w1, w2, w3);
  float c1 = dot4f(Rd + 4,  w0, w1, w2, w3);
  float c2 = dot4f(Rd + 8,  w0, w1, w2, w3);
  float c3 = dot4f(Rd + 12, w0, w1, w2, w3);
  float p0 = dot4f(sK + 0, c0, c1, c2, c3);
  float p1 = dot4f(sK + 4, c0, c1, c2, c3);
  float p2 = dot4f(sK + 8, c0, c1, c2, c3);
  if (p2 > EPSF) {
    float sx = p0 / p2, sy = p1 / p2;                 // f32 IEEE division
    float pxf = rintf(((sx + 1.0f) * 0.5f) * 255.0f); // jnp.round = half-to-even
    float pyf = rintf(((sy + 1.0f) * 0.5f) * 255.0f);
    if (pxf >= 0.0f && pxf <= 255.0f && pyf >= 0.0f && pyf <= 255.0f) {
      int idx = (int)pyf * WF + (int)pxf;
      unsigned zbits = __float_as_uint(p2);           // p2>0 -> order-preserving
      unsigned long long key = ((unsigned long long)zbits << 32) | (unsigned)n;
      atomicMin(&zwin[(size_t)bv * NPIX + idx], key);
    }
  }
}

// gather for one point g: full 64-ch record (4 full 128B lines from LLC-warm
// tf) + colors + depth. No returns (cooperative-safe).
__device__ __forceinline__ void gather_point(int g, unsigned long long key,
                                             const float* __restrict__ tf,
                                             const float* __restrict__ colr,
                                             float* __restrict__ out0,
                                             float* __restrict__ out1,
                                             float* __restrict__ out2) {
  int bv = g >> 16;
  int pix = g & (NPIX - 1);
  bool hit = (key != ~0ULL);
  int n = (int)(key & 0xffffffffULL);
  float4 f[16];
  if (hit) {
    const float4* src = (const float4*)(tf + ((size_t)bv * NPIX + n) * CF);
    #pragma unroll
    for (int i = 0; i < 16; ++i) f[i] = src[i];
  } else {
    #pragma unroll
    for (int i = 0; i < 16; ++i) f[i] = make_float4(0.f, 0.f, 0.f, 0.f);
  }
  float* o0 = out0 + (size_t)bv * CF * NPIX + pix;
  const float* fs = (const float*)f;
  #pragma unroll
  for (int c = 0; c < CF; ++c)
    __builtin_nontemporal_store(fs[c], &o0[(size_t)c * NPIX]);

  int b = bv >> 1, v = bv & 1;         // V_ == 2
  const float* cb = colr + (size_t)bv * 3 * NPIX;
  float* o1 = out1 + (size_t)(v * B_ + b) * 3 * NPIX + pix;
  if (hit) {
    float z = __uint_as_float((unsigned)(key >> 32));
    __builtin_nontemporal_store((z < BIGF) ? z : 0.0f, &out2[g]);
    #pragma unroll
    for (int ch = 0; ch < 3; ++ch)
      __builtin_nontemporal_store(cb[(size_t)ch * NPIX + n] * 0.5f + 0.5f,
                                  &o1[(size_t)ch * NPIX]);
  } else {
    __builtin_nontemporal_store(0.0f, &out2[g]);
    #pragma unroll
    for (int ch = 0; ch < 3; ++ch)
      __builtin_nontemporal_store(0.0f, &o1[(size_t)ch * NPIX]);
  }
}

// ============ single cooperative kernel: 1024 blocks x 256 ============
// Phase A: zwin init (1 pt/thread) + mats + transpose (4 tiles/blk) +
//          resize (3 tiles/blk).   grid.sync()
// Phase B: splat (1 tile/blk).     grid.sync()
// Phase C: gather (1 pt/thread, zwin read once).
// __launch_bounds__(256,4): VGPR<=128 -> 4 blocks/CU -> 1024 blocks
// co-resident (cooperative launch requirement).
__global__ __launch_bounds__(256, 4) void mega_k(
    const float* __restrict__ depths, const float* __restrict__ colors,
    const float* __restrict__ feats, const float* __restrict__ K,
    const float* __restrict__ srcRTinv, const float* __restrict__ dstRT,
    float* __restrict__ out0, float* __restrict__ out1,
    float* __restrict__ out2, unsigned long long* __restrict__ zwin,
    float* __restrict__ colr, float* __restrict__ mats,
    float* __restrict__ tf) {
  int bid = blockIdx.x, t = threadIdx.x;
  int g0 = bid * 256 + t;              // grid covers NPT exactly

  // ---- Phase A ----
  zwin[g0] = ~0ULL;
  if (g0 < B_) mats_compute(K, g0, mats);
  #pragma unroll
  for (int i = 0; i < 4; ++i) transp_tile(i * NBLK + bid, t, feats, tf);
  #pragma unroll
  for (int i = 0; i < 3; ++i) resize_body((i * NBLK + bid) * 256 + t, colors, colr);

  cg::this_grid().sync();

  // ---- Phase B ----
  splat_body(g0, depths, mats, srcRTinv, dstRT, zwin);

  cg::this_grid().sync();

  // ---- Phase C ----
  gather_point(g0, zwin[g0], tf, colr, out0, out1, out2);
}

// ============ fallback path (exact r5 structure) ============
__global__ void init_k(const float* __restrict__ K,
                       float* __restrict__ mats,
                       unsigned long long* __restrict__ zwin) {
  int g = blockIdx.x * blockDim.x + threadIdx.x;
  zwin[g] = ~0ULL;                     // grid == NPT exactly
  if (g < B_) mats_compute(K, g, mats);
}

__global__ void work_k(const float* __restrict__ depths,
                       const float* __restrict__ mats,
                       const float* __restrict__ srcRTinv,
                       const float* __restrict__ dstRT,
                       unsigned long long* __restrict__ zwin,
                       const float* __restrict__ feats,
                       float* __restrict__ tf,
                       const float* __restrict__ colors,
                       float* __restrict__ colr) {
  int bid = blockIdx.x;
  int nTP = (int)gridDim.x - RESIZE_BLKS - NBLK;
  int t = threadIdx.x;
  if (bid < nTP) { transp_tile(bid, t, feats, tf); return; }
  int rb = bid - nTP;
  if (rb < RESIZE_BLKS) { resize_body(rb * 256 + t, colors, colr); return; }
  int g = (rb - RESIZE_BLKS) * 256 + t;
  splat_body(g, depths, mats, srcRTinv, dstRT, zwin);
}

__global__ void gather3_k(const unsigned long long* __restrict__ zwin,
                          const float* __restrict__ tf,
                          const float* __restrict__ colr,
                          float* __restrict__ out0,
                          float* __restrict__ out1,
                          float* __restrict__ out2) {
  int bid = blockIdx.x;
  int grp = bid >> 10;
  int g   = (bid & (NBLK - 1)) * 256 + threadIdx.x;
  int bv  = g >> 16;
  int pix = g & (NPIX - 1);
  unsigned long long key = zwin[g];
  bool hit = (key != ~0ULL);
  int n = (int)(key & 0xffffffffULL);

  if (grp < 2) {
    float4 f[8];
    if (hit) {
      const float4* src =
          (const float4*)(tf + ((size_t)bv * NPIX + n) * CF + grp * 32);
      #pragma unroll
      for (int i = 0; i < 8; ++i) f[i] = src[i];
    } else {
      #pragma unroll
      for (int i = 0; i < 8; ++i) f[i] = make_float4(0.f, 0.f, 0.f, 0.f);
    }
    float* o0 = out0 + (size_t)bv * CF * NPIX + (size_t)(grp * 32) * NPIX + pix;
    const float* fs = (const float*)f;
    #pragma unroll
    for (int c = 0; c < 32; ++c)
      __builtin_nontemporal_store(fs[c], &o0[(size_t)c * NPIX]);
  } else {
    int b = bv >> 1, v = bv & 1;
    const float* cb = colr + (size_t)bv * 3 * NPIX;
    float* o1 = out1 + (size_t)(v * B_ + b) * 3 * NPIX + pix;
    if (hit) {
      float z = __uint_as_float((unsigned)(key >> 32));
      __builtin_nontemporal_store((z < BIGF) ? z : 0.0f, &out2[g]);
      #pragma unroll
      for (int ch = 0; ch < 3; ++ch)
        __builtin_nontemporal_store(cb[(size_t)ch * NPIX + n] * 0.5f + 0.5f,
                                    &o1[(size_t)ch * NPIX]);
    } else {
      __builtin_nontemporal_store(0.0f, &out2[g]);
      #pragma unroll
      for (int ch = 0; ch < 3; ++ch)
        __builtin_nontemporal_store(0.0f, &o1[(size_t)ch * NPIX]);
    }
  }
}

// no-tf fallback gather (exact r0 passing kernel)
__global__ void gather_k(const unsigned long long* __restrict__ zwin,
                         const float* __restrict__ feats,
                         const float* __restrict__ colr,
                         float* __restrict__ out0,
                         float* __restrict__ out1,
                         float* __restrict__ out2) {
  int bid = blockIdx.x;
  int grp = bid >> 10;
  int g   = (bid & (NBLK - 1)) * 256 + threadIdx.x;
  int bv  = g >> 16;
  int pix = g & (NPIX - 1);
  unsigned long long key = zwin[g];
  bool hit = (key != ~0ULL);
  int n = (int)(key & 0xffffffffULL);

  if (grp < 4) {
    int c0 = grp * 16;
    const float* fb = feats + (size_t)bv * CF * NPIX + (size_t)c0 * NPIX;
    float* o0 = out0 + (size_t)bv * CF * NPIX + (size_t)c0 * NPIX + pix;
    if (hit) {
      #pragma unroll
      for (int c = 0; c < 16; ++c)
        __builtin_nontemporal_store(fb[(size_t)c * NPIX + n], &o0[(size_t)c * NPIX]);
    } else {
      #pragma unroll
      for (int c = 0; c < 16; ++c)
        __builtin_nontemporal_store(0.0f, &o0[(size_t)c * NPIX]);
    }
  } else {
    int b = bv >> 1, v = bv & 1;
    const float* cb = colr + (size_t)bv * 3 * NPIX;
    float* o1 = out1 + (size_t)(v * B_ + b) * 3 * NPIX + pix;
    if (hit) {
      float z = __uint_as_float((unsigned)(key >> 32));
      __builtin_nontemporal_store((z < BIGF) ? z : 0.0f, &out2[g]);
      #pragma unroll
      for (int ch = 0; ch < 3; ++ch)
        __builtin_nontemporal_store(cb[(size_t)ch * NPIX + n] * 0.5f + 0.5f,
                                    &o1[(size_t)ch * NPIX]);
    } else {
      __builtin_nontemporal_store(0.0f, &out2[g]);
      #pragma unroll
      for (int ch = 0; ch < 3; ++ch)
        __builtin_nontemporal_store(0.0f, &o1[(size_t)ch * NPIX]);
    }
  }
}

extern "C" void kernel_launch(void* const* d_in, const int* in_sizes, int n_in,
                              void* d_out, int out_size, void* d_ws, size_t ws_size,
                              hipStream_t stream) {
  const float* depths     = (const float*)d_in[0];
  const float* colors     = (const float*)d_in[1];
  const float* feats      = (const float*)d_in[2];
  const float* K          = (const float*)d_in[3];
  const float* src_RTinvs = (const float*)d_in[5];
  const float* dst_RTs    = (const float*)d_in[6];

  float* out0 = (float*)d_out;                                  // (B,V,64,256,256)
  float* out1 = out0 + (size_t)B_ * V_ * CF * NPIX;             // (V,B,3,256,256)
  float* out2 = out1 + (size_t)V_ * B_ * 3 * NPIX;              // (B,V,1,256,256)

  unsigned long long* zwin = (unsigned long long*)d_ws;         // 2 MiB
  float* colr = (float*)(zwin + NPT);                           // 3 MiB
  float* mats = colr + (size_t)B_ * V_ * 3 * NPIX;              // 256 B
  float* tf   = (float*)((char*)d_ws + WS_BASE);                // 64 MiB (16B-aligned)

  const bool use_tf = (ws_size >= WS_BASE + TF_BYTES);

  if (use_tf) {
    void* kargs[] = {(void*)&depths, (void*)&colors, (void*)&feats, (void*)&K,
                     (void*)&src_RTinvs, (void*)&dst_RTs, (void*)&out0,
                     (void*)&out1, (void*)&out2, (void*)&zwin, (void*)&colr,
                     (void*)&mats, (void*)&tf};
    hipError_t err = hipLaunchCooperativeKernel((const void*)mega_k, dim3(NBLK),
                                                dim3(256), kargs, 0, stream);
    if (err == hipSuccess) return;
    (void)hipGetLastError();           // clear error state, fall through
  }

  // fallback: exact r5 3-launch structure
  init_k<<<NBLK, 256, 0, stream>>>(K, mats, zwin);
  int work_grid = (use_tf ? TP_BLKS : 0) + RESIZE_BLKS + NBLK;
  work_k<<<work_grid, 256, 0, stream>>>(depths, mats, src_RTinvs, dst_RTs, zwin,
                                        feats, tf, colors, colr);
  if (use_tf)
    gather3_k<<<3 * NBLK, 256, 0, stream>>>(zwin, tf, colr, out0, out1, out2);
  else
    gather_k<<<5 * NBLK, 256, 0, stream>>>(zwin, feats, colr, out0, out1, out2);
}

// Round 7
// 183.703 us; speedup vs baseline: 2.3658x; 2.3658x over previous
//
#include <hip/hip_runtime.h>
#include <stdint.h>

#pragma clang fp contract(off)

namespace {
constexpr int B_ = 2, V_ = 2, HC = 512, WC = 512, HF = 256, WF = 256, CF = 64;
constexpr int NPIX = HF * WF;                 // 65536
constexpr float EPSF = 1e-4f;
constexpr float BIGF = 1e10f;                 // exactly representable in f32
constexpr int NPT = B_ * V_ * NPIX;           // 262144
constexpr int NBLK = 1024;                    // NPT/256
constexpr int RESIZE_BLKS = (B_ * V_ * 3 * NPIX) / 256;   // 3072
constexpr int T512_BLKS = B_ * V_ * (NPIX / 512);         // 512 transpose blocks
// workspace layout: zwin (2 MiB) | colr (3 MiB) | mats (256 B) | tf (64 MiB, optional)
constexpr size_t WS_BASE = (size_t)NPT * 8 + (size_t)B_ * V_ * 3 * NPIX * 4 + 256;
constexpr size_t TF_BYTES = (size_t)NPT * CF * 4;
}

// NON-FMA ascending f32 dot4 (fp contract off TU-wide keeps mul/add separate).
__device__ __forceinline__ float dot4f(const float* __restrict__ r,
                                       float v0, float v1, float v2, float v3) {
  float t = r[0] * v0;
  t = t + r[1] * v1;
  t = t + r[2] * v2;
  t = t + r[3] * v3;
  return t;
}

// per-batch sK / sKinv (f64 adjugate -> f32). Executed by thread b (b < B_).
__device__ void mats_compute(const float* __restrict__ K, int b,
                             float* __restrict__ mats) {
  const float rowscale[4] = {0.5f, 0.5f, 1.0f, 1.0f};
  float sK[16];
  for (int i = 0; i < 4; ++i)
    for (int j = 0; j < 4; ++j)
      sK[i*4+j] = K[b*16 + i*4 + j] * rowscale[i];
  double m[16];
  for (int i = 0; i < 16; ++i) m[i] = (double)sK[i];
  double inv[16];
  inv[0]  =  m[5]*m[10]*m[15] - m[5]*m[11]*m[14] - m[9]*m[6]*m[15] + m[9]*m[7]*m[14] + m[13]*m[6]*m[11] - m[13]*m[7]*m[10];
  inv[4]  = -m[4]*m[10]*m[15] + m[4]*m[11]*m[14] + m[8]*m[6]*m[15] - m[8]*m[7]*m[14] - m[12]*m[6]*m[11] + m[12]*m[7]*m[10];
  inv[8]  =  m[4]*m[9]*m[15]  - m[4]*m[11]*m[13] - m[8]*m[5]*m[15] + m[8]*m[7]*m[13] + m[12]*m[5]*m[11] - m[12]*m[7]*m[9];
  inv[12] = -m[4]*m[9]*m[14]  + m[4]*m[10]*m[13] + m[8]*m[5]*m[14] - m[8]*m[6]*m[13] - m[12]*m[5]*m[10] + m[12]*m[6]*m[9];
  inv[1]  = -m[1]*m[10]*m[15] + m[1]*m[11]*m[14] + m[9]*m[2]*m[15] - m[9]*m[3]*m[14] - m[13]*m[2]*m[11] + m[13]*m[3]*m[10];
  inv[5]  =  m[0]*m[10]*m[15] - m[0]*m[11]*m[14] - m[8]*m[2]*m[15] + m[8]*m[3]*m[14] + m[12]*m[2]*m[11] - m[12]*m[3]*m[10];
  inv[9]  = -m[0]*m[9]*m[15]  + m[0]*m[11]*m[13] + m[8]*m[1]*m[15] - m[8]*m[3]*m[13] - m[12]*m[1]*m[11] + m[12]*m[3]*m[9];
  inv[13] =  m[0]*m[9]*m[14]  - m[0]*m[10]*m[13] - m[8]*m[1]*m[14] + m[8]*m[2]*m[13] + m[12]*m[1]*m[10] - m[12]*m[2]*m[9];
  inv[2]  =  m[1]*m[6]*m[15]  - m[1]*m[7]*m[14]  - m[5]*m[2]*m[15] + m[5]*m[3]*m[14] + m[13]*m[2]*m[7]  - m[13]*m[3]*m[6];
  inv[6]  = -m[0]*m[6]*m[15]  + m[0]*m[7]*m[14]  + m[4]*m[2]*m[15] - m[4]*m[3]*m[14] - m[12]*m[2]*m[7]  + m[12]*m[3]*m[6];
  inv[10] =  m[0]*m[5]*m[15]  - m[0]*m[7]*m[13]  - m[4]*m[1]*m[15] + m[4]*m[3]*m[13] + m[12]*m[1]*m[7]  - m[12]*m[3]*m[5];
  inv[14] = -m[0]*m[5]*m[14]  + m[0]*m[6]*m[13]  + m[4]*m[1]*m[14] - m[4]*m[2]*m[13] - m[12]*m[1]*m[6]  + m[12]*m[2]*m[5];
  inv[3]  = -m[1]*m[6]*m[11]  + m[1]*m[7]*m[10]  + m[5]*m[2]*m[11] - m[5]*m[3]*m[10] - m[9]*m[2]*m[7]   + m[9]*m[3]*m[6];
  inv[7]  =  m[0]*m[6]*m[11]  - m[0]*m[7]*m[10]  - m[4]*m[2]*m[11] + m[4]*m[3]*m[10] + m[8]*m[2]*m[7]   - m[8]*m[3]*m[6];
  inv[11] = -m[0]*m[5]*m[11]  + m[0]*m[7]*m[9]   + m[4]*m[1]*m[11] - m[4]*m[3]*m[9]  - m[8]*m[1]*m[7]   + m[8]*m[3]*m[5];
  inv[15] =  m[0]*m[5]*m[10]  - m[0]*m[6]*m[9]   - m[4]*m[1]*m[10] + m[4]*m[2]*m[9]  + m[8]*m[1]*m[6]   - m[8]*m[2]*m[5];
  double det = m[0]*inv[0] + m[1]*inv[4] + m[2]*inv[8] + m[3]*inv[12];
  double idet = 1.0 / det;
  for (int i = 0; i < 16; ++i) {
    mats[b*32 + i]      = sK[i];
    mats[b*32 + 16 + i] = (float)(inv[i] * idet);
  }
}

// antialiased linear 2x downsample of colors (r5 arithmetic).
__device__ __forceinline__ void resize_body(int g,
                                            const float* __restrict__ colors,
                                            float* __restrict__ colr) {
  int pc  = g >> 16;            // bv*3 + ch
  int pix = g & (NPIX - 1);
  int y = pix >> 8, x = pix & (WF - 1);
  const float* src = colors + (size_t)pc * HC * WC;
  const float W37 = (float)(3.0 / 7.0), W17 = (float)(1.0 / 7.0);
  float wy[4] = {0.125f, 0.375f, 0.375f, 0.125f};
  float wx[4] = {0.125f, 0.375f, 0.375f, 0.125f};
  if (y == 0)      { wy[0] = 0.f; wy[1] = W37; wy[2] = W37; wy[3] = W17; }
  if (y == HF - 1) { wy[0] = W17; wy[1] = W37; wy[2] = W37; wy[3] = 0.f; }
  if (x == 0)      { wx[0] = 0.f; wx[1] = W37; wx[2] = W37; wx[3] = W17; }
  if (x == WF - 1) { wx[0] = W17; wx[1] = W37; wx[2] = W37; wx[3] = 0.f; }
  int jy0 = 2 * y - 1, jx0 = 2 * x - 1;
  float acc = 0.f;
  #pragma unroll
  for (int ty = 0; ty < 4; ++ty) {
    if (wy[ty] == 0.f) continue;       // also guards OOB rows
    int jy = jy0 + ty;
    float rs = 0.f;
    #pragma unroll
    for (int tx = 0; tx < 4; ++tx) {
      if (wx[tx] == 0.f) continue;     // also guards OOB cols
      rs = rs + wx[tx] * src[(size_t)jy * WC + (jx0 + tx)];
    }
    acc = acc + wy[ty] * rs;
  }
  colr[g] = acc;
}

// f32 projection + z-buffer atomicMin (r5 PASSING numerics — do not touch).
__device__ __forceinline__ void splat_body(int g,
                                           const float* __restrict__ depths,
                                           const float* __restrict__ mats,
                                           const float* __restrict__ srcRTinv,
                                           const float* __restrict__ dstRT,
                                           unsigned long long* __restrict__ zwin) {
  int bv = g >> 16;
  int n  = g & (NPIX - 1);
  int b  = bv / V_;
  int y = n >> 8, x = n & (WF - 1);
  float d = depths[(size_t)bv * HC * WC + (size_t)(2 * y + 1) * WC + (2 * x + 1)];
  const float step32 = 2.0f / 255.0f;
  float xf = (float)x * step32 - 1.0f;
  float yf = (float)y * step32 - 1.0f;
  float pr0 = xf * d, pr1 = yf * d, pr2 = d, pr3 = 1.0f;
  const float* sK  = mats + b * 32;
  const float* sKi = mats + b * 32 + 16;
  const float* Rs  = srcRTinv + (size_t)bv * 16;
  const float* Rd  = dstRT + (size_t)b * 16;     // dst_RTs[:,0]
  float a0 = dot4f(sKi + 0,  pr0, pr1, pr2, pr3);
  float a1 = dot4f(sKi + 4,  pr0, pr1, pr2, pr3);
  float a2 = dot4f(sKi + 8,  pr0, pr1, pr2, pr3);
  float a3 = dot4f(sKi + 12, pr0, pr1, pr2, pr3);
  float w0 = dot4f(Rs + 0,  a0, a1, a2, a3);
  float w1 = dot4f(Rs + 4,  a0, a1, a2, a3);
  float w2 = dot4f(Rs + 8,  a0, a1, a2, a3);
  float w3 = dot4f(Rs + 12, a0, a1, a2, a3);
  float c0 = dot4f(Rd + 0,  w0, w1, w2, w3);
  float c1 = dot4f(Rd + 4,  w0, w1, w2, w3);
  float c2 = dot4f(Rd + 8,  w0, w1, w2, w3);
  float c3 = dot4f(Rd + 12, w0, w1, w2, w3);
  float p0 = dot4f(sK + 0, c0, c1, c2, c3);
  float p1 = dot4f(sK + 4, c0, c1, c2, c3);
  float p2 = dot4f(sK + 8, c0, c1, c2, c3);
  if (p2 > EPSF) {
    float sx = p0 / p2, sy = p1 / p2;                 // f32 IEEE division
    float pxf = rintf(((sx + 1.0f) * 0.5f) * 255.0f); // jnp.round = half-to-even
    float pyf = rintf(((sy + 1.0f) * 0.5f) * 255.0f);
    if (pxf >= 0.0f && pxf <= 255.0f && pyf >= 0.0f && pyf <= 255.0f) {
      int idx = (int)pyf * WF + (int)pxf;
      unsigned zbits = __float_as_uint(p2);           // p2>0 -> order-preserving
      unsigned long long key = ((unsigned long long)zbits << 32) | (unsigned)n;
      atomicMin(&zwin[(size_t)bv * NPIX + idx], key);
    }
  }
}

// --- init: zwin init + per-batch matrices. grid = 1024 x 256 ---
__global__ void init_k(const float* __restrict__ K,
                       float* __restrict__ mats,
                       unsigned long long* __restrict__ zwin) {
  int g = blockIdx.x * blockDim.x + threadIdx.x;
  zwin[g] = ~0ULL;
  if (g < B_) mats_compute(K, g, mats);
}

// --- fused mix: 512px-tile slab transpose + resize + splat (independent).
// Transpose blocks [0, 512): block = 512 px x 64 ch in 4 passes of 16-ch
//   slabs through 33KB LDS. Per wave-instruction the global READ is 1KB
//   CONTIGUOUS from one plane (block covers a 2KB run per plane) and the
//   global WRITE is 1KB contiguous in slab-major tf4[bv][slab][pix][16]
//   (pass writes a sequential 32KB) -> long DRAM runs on both sides.
//   LDS stride 516 words: store banks = b128 floor; read (16j+4m+p)%32 is
//   exactly 2-way (free, m136).
// Blocks [512, 512+3072): resize.  Blocks [.., +1024): splat.
__global__ void mix_k(const float* __restrict__ depths,
                      const float* __restrict__ mats,
                      const float* __restrict__ srcRTinv,
                      const float* __restrict__ dstRT,
                      unsigned long long* __restrict__ zwin,
                      const float* __restrict__ feats,
                      float* __restrict__ tf,
                      const float* __restrict__ colors,
                      float* __restrict__ colr) {
  __shared__ float lds[16 * 516];      // 33 KB
  int bid = blockIdx.x;
  int t = threadIdx.x;

  if (bid < T512_BLKS) {               // ---- transpose ----
    int bv = bid >> 7;                 // 128 tiles per bv
    int pix0 = (bid & 127) << 9;       // 512 px per tile
    int w = t >> 6, l = t & 63;
    int j = l & 3, prel = l >> 2;
    #pragma unroll
    for (int s = 0; s < 4; ++s) {
      if (s) __syncthreads();          // LDS reuse fence
      float4 v[4][2];
      #pragma unroll
      for (int k = 0; k < 4; ++k) {    // wave w loads planes 16s+4w+k
        int c = 16 * s + 4 * w + k;
        const float* fp = feats + ((size_t)bv * CF + c) * NPIX + pix0;
        v[k][0] = *(const float4*)(fp + 4 * l);         // 1KB contiguous/instr
        v[k][1] = *(const float4*)(fp + 256 + 4 * l);
      }
      #pragma unroll
      for (int k = 0; k < 4; ++k) {
        int cl = 4 * w + k;
        *(float4*)(&lds[cl * 516 + 4 * l])       = v[k][0];
        *(float4*)(&lds[cl * 516 + 256 + 4 * l]) = v[k][1];
      }
      __syncthreads();
      float* tb = tf + ((size_t)(bv * 4 + s) * NPIX + pix0) * 16;
      #pragma unroll
      for (int it = 0; it < 8; ++it) { // 16 records/instr, 1KB contiguous
        int p = w * 128 + it * 16 + prel;
        float4 o;
        o.x = lds[(4 * j + 0) * 516 + p];
        o.y = lds[(4 * j + 1) * 516 + p];
        o.z = lds[(4 * j + 2) * 516 + p];
        o.w = lds[(4 * j + 3) * 516 + p];
        *(float4*)(tb + (size_t)p * 16 + 4 * j) = o;
      }
    }
    return;
  }

  int rb = bid - T512_BLKS;
  if (rb < RESIZE_BLKS) {              // ---- color resize ----
    resize_body(rb * 256 + t, colors, colr);
    return;
  }

  // ---- splat ----
  int g = (rb - RESIZE_BLKS) * 256 + t;
  splat_body(g, depths, mats, srcRTinv, dstRT, zwin);
}

// --- gather from slab-major tf4, 3 block-groups:
// grp 0/1: 32 feat channels = 2 slabs x one full 64B line each.
// grp 2:   colors (V,B,3,H,W layout!) + depth.
__global__ void gather3_k(const unsigned long long* __restrict__ zwin,
                          const float* __restrict__ tf,
                          const float* __restrict__ colr,
                          float* __restrict__ out0,
                          float* __restrict__ out1,
                          float* __restrict__ out2) {
  int bid = blockIdx.x;
  int grp = bid >> 10;
  int g   = (bid & (NBLK - 1)) * 256 + threadIdx.x;
  int bv  = g >> 16;
  int pix = g & (NPIX - 1);
  unsigned long long key = zwin[g];
  bool hit = (key != ~0ULL);
  int n = (int)(key & 0xffffffffULL);

  if (grp < 2) {                       // slabs 2*grp, 2*grp+1 (32 channels)
    float4 f[8];
    if (hit) {
      const float4* s0 =
          (const float4*)(tf + ((size_t)(bv * 4 + grp * 2) * NPIX + n) * 16);
      const float4* s1 =
          (const float4*)(tf + ((size_t)(bv * 4 + grp * 2 + 1) * NPIX + n) * 16);
      #pragma unroll
      for (int i = 0; i < 4; ++i) f[i] = s0[i];
      #pragma unroll
      for (int i = 0; i < 4; ++i) f[4 + i] = s1[i];
    } else {
      #pragma unroll
      for (int i = 0; i < 8; ++i) f[i] = make_float4(0.f, 0.f, 0.f, 0.f);
    }
    float* o0 = out0 + (size_t)bv * CF * NPIX + (size_t)(grp * 32) * NPIX + pix;
    const float* fs = (const float*)f;
    #pragma unroll
    for (int c = 0; c < 32; ++c)
      __builtin_nontemporal_store(fs[c], &o0[(size_t)c * NPIX]);
  } else {                             // colors + depth
    int b = bv >> 1, v = bv & 1;
    const float* cb = colr + (size_t)bv * 3 * NPIX;
    float* o1 = out1 + (size_t)(v * B_ + b) * 3 * NPIX + pix;
    if (hit) {
      float z = __uint_as_float((unsigned)(key >> 32));
      __builtin_nontemporal_store((z < BIGF) ? z : 0.0f, &out2[g]);
      #pragma unroll
      for (int ch = 0; ch < 3; ++ch)
        __builtin_nontemporal_store(cb[(size_t)ch * NPIX + n] * 0.5f + 0.5f,
                                    &o1[(size_t)ch * NPIX]);
    } else {
      __builtin_nontemporal_store(0.0f, &out2[g]);
      #pragma unroll
      for (int ch = 0; ch < 3; ++ch)
        __builtin_nontemporal_store(0.0f, &o1[(size_t)ch * NPIX]);
    }
  }
}

// --- no-tf fallback: r5 work_k (4x4 reg transpose skipped) + r0 gather ---
__global__ void work_fb_k(const float* __restrict__ depths,
                          const float* __restrict__ mats,
                          const float* __restrict__ srcRTinv,
                          const float* __restrict__ dstRT,
                          unsigned long long* __restrict__ zwin,
                          const float* __restrict__ colors,
                          float* __restrict__ colr) {
  int bid = blockIdx.x;
  int t = threadIdx.x;
  if (bid < RESIZE_BLKS) { resize_body(bid * 256 + t, colors, colr); return; }
  int g = (bid - RESIZE_BLKS) * 256 + t;
  splat_body(g, depths, mats, srcRTinv, dstRT, zwin);
}

__global__ void gather_k(const unsigned long long* __restrict__ zwin,
                         const float* __restrict__ feats,
                         const float* __restrict__ colr,
                         float* __restrict__ out0,
                         float* __restrict__ out1,
                         float* __restrict__ out2) {
  int bid = blockIdx.x;
  int grp = bid >> 10;
  int g   = (bid & (NBLK - 1)) * 256 + threadIdx.x;
  int bv  = g >> 16;
  int pix = g & (NPIX - 1);
  unsigned long long key = zwin[g];
  bool hit = (key != ~0ULL);
  int n = (int)(key & 0xffffffffULL);

  if (grp < 4) {
    int c0 = grp * 16;
    const float* fb = feats + (size_t)bv * CF * NPIX + (size_t)c0 * NPIX;
    float* o0 = out0 + (size_t)bv * CF * NPIX + (size_t)c0 * NPIX + pix;
    if (hit) {
      #pragma unroll
      for (int c = 0; c < 16; ++c)
        __builtin_nontemporal_store(fb[(size_t)c * NPIX + n], &o0[(size_t)c * NPIX]);
    } else {
      #pragma unroll
      for (int c = 0; c < 16; ++c)
        __builtin_nontemporal_store(0.0f, &o0[(size_t)c * NPIX]);
    }
  } else {
    int b = bv >> 1, v = bv & 1;
    const float* cb = colr + (size_t)bv * 3 * NPIX;
    float* o1 = out1 + (size_t)(v * B_ + b) * 3 * NPIX + pix;
    if (hit) {
      float z = __uint_as_float((unsigned)(key >> 32));
      __builtin_nontemporal_store((z < BIGF) ? z : 0.0f, &out2[g]);
      #pragma unroll
      for (int ch = 0; ch < 3; ++ch)
        __builtin_nontemporal_store(cb[(size_t)ch * NPIX + n] * 0.5f + 0.5f,
                                    &o1[(size_t)ch * NPIX]);
    } else {
      __builtin_nontemporal_store(0.0f, &out2[g]);
      #pragma unroll
      for (int ch = 0; ch < 3; ++ch)
        __builtin_nontemporal_store(0.0f, &o1[(size_t)ch * NPIX]);
    }
  }
}

extern "C" void kernel_launch(void* const* d_in, const int* in_sizes, int n_in,
                              void* d_out, int out_size, void* d_ws, size_t ws_size,
                              hipStream_t stream) {
  const float* depths     = (const float*)d_in[0];
  const float* colors     = (const float*)d_in[1];
  const float* feats      = (const float*)d_in[2];
  const float* K          = (const float*)d_in[3];
  const float* src_RTinvs = (const float*)d_in[5];
  const float* dst_RTs    = (const float*)d_in[6];

  float* out0 = (float*)d_out;                                  // (B,V,64,256,256)
  float* out1 = out0 + (size_t)B_ * V_ * CF * NPIX;             // (V,B,3,256,256)
  float* out2 = out1 + (size_t)V_ * B_ * 3 * NPIX;              // (B,V,1,256,256)

  unsigned long long* zwin = (unsigned long long*)d_ws;         // 2 MiB
  float* colr = (float*)(zwin + NPT);                           // 3 MiB
  float* mats = colr + (size_t)B_ * V_ * 3 * NPIX;              // 256 B
  float* tf   = (float*)((char*)d_ws + WS_BASE);                // 64 MiB (16B-aligned)

  const bool use_tf = (ws_size >= WS_BASE + TF_BYTES);

  init_k<<<NBLK, 256, 0, stream>>>(K, mats, zwin);
  if (use_tf) {
    mix_k<<<T512_BLKS + RESIZE_BLKS + NBLK, 256, 0, stream>>>(
        depths, mats, src_RTinvs, dst_RTs, zwin, feats, tf, colors, colr);
    gather3_k<<<3 * NBLK, 256, 0, stream>>>(zwin, tf, colr, out0, out1, out2);
  } else {
    work_fb_k<<<RESIZE_BLKS + NBLK, 256, 0, stream>>>(
        depths, mats, src_RTinvs, dst_RTs, zwin, colors, colr);
    gather_k<<<5 * NBLK, 256, 0, stream>>>(zwin, feats, colr, out0, out1, out2);
  }
}